// Round 2
// baseline (820.464 us; speedup 1.0000x reference)
//
#include <hip/hip_runtime.h>
#include <cmath>

#define NB 8
#define NPTS 2048
#define NE (NB * NPTS)
#define THREADS 512
#define ROWS_PER_BLOCK 32
#define LANES 16

#if defined(__has_builtin)
#if __has_builtin(__builtin_amdgcn_exp2f)
#define FAST_EXP2(x) __builtin_amdgcn_exp2f(x)
#else
#define FAST_EXP2(x) exp2f(x)
#endif
#if __has_builtin(__builtin_amdgcn_logf)
#define FAST_LOG2(x) __builtin_amdgcn_logf(x)
#else
#define FAST_LOG2(x) log2f(x)
#endif
#else
#define FAST_EXP2(x) exp2f(x)
#define FAST_LOG2(x) log2f(x)
#endif

// One Sinkhorn "phase": computes, for every row i of each batch,
//   softmin_eps(C, h)_i = -eps * LSE_j( h_j - C_ij/eps )
// for BOTH sides (f-side rows = x pts vs y cols; g-side rows = y vs x),
// then writes out = c_old*prev + c_new*softmin.
__global__ __launch_bounds__(THREADS, 8) void sinkhorn_phase(
    const float* __restrict__ x, const float* __restrict__ y,
    const float* __restrict__ loga, const float* __restrict__ logb,
    const float* __restrict__ f_prev, const float* __restrict__ g_prev,
    float* __restrict__ f_next, float* __restrict__ g_next,
    float eps, float inv_eps, float c_old, float c_new)
{
    __shared__ float4 tile[NPTS];  // {col.x, col.y, h*log2e, pad}

    const int blk = blockIdx.x;
    const int side = blk >> 9;          // 0: f-side, 1: g-side (512 row-blocks/side)
    const int rblk = blk & 511;
    const int batch = rblk >> 6;        // 64 row-tiles per batch
    const int rowTile = rblk & 63;

    const float* rowPts; const float* colPts; const float* hlog;
    const float* hpot; const float* ownPrev; float* outPot;
    if (side == 0) { rowPts = x; colPts = y; hlog = logb; hpot = g_prev; ownPrev = f_prev; outPot = f_next; }
    else           { rowPts = y; colPts = x; hlog = loga; hpot = f_prev; ownPrev = g_prev; outPot = g_next; }

    const float LOG2E = 1.4426950408889634f;

    // Stage the full column tile (points + h) for this batch into LDS.
    const float* cp = colPts + (size_t)batch * NPTS * 2;
    const float* hl = hlog + (size_t)batch * NPTS;
    const float* pp = hpot + (size_t)batch * NPTS;
    for (int j = threadIdx.x; j < NPTS; j += THREADS) {
        float2 p = ((const float2*)cp)[j];
        float h2 = (hl[j] + pp[j] * inv_eps) * LOG2E;   // log2-domain h
        tile[j] = make_float4(p.x, p.y, h2, 0.0f);
    }
    __syncthreads();

    const int lane = threadIdx.x & (LANES - 1);
    const int row = rowTile * ROWS_PER_BLOCK + (threadIdx.x >> 4);
    const float2 rp = ((const float2*)(rowPts + (size_t)batch * NPTS * 2))[row];
    const float nscale = -0.5f * inv_eps * LOG2E;       // -(1/(2 eps)) * log2e

    // Pass 1: row max (log2 domain)
    float m = -3.4e38f;
    #pragma unroll 8
    for (int j = lane; j < NPTS; j += LANES) {
        float4 t4 = tile[j];
        float dx = rp.x - t4.x, dy = rp.y - t4.y;
        float c = fmaf(dy, dy, dx * dx);
        float t = fmaf(nscale, c, t4.z);
        m = fmaxf(m, t);
    }
    m = fmaxf(m, __shfl_xor(m, 8));
    m = fmaxf(m, __shfl_xor(m, 4));
    m = fmaxf(m, __shfl_xor(m, 2));
    m = fmaxf(m, __shfl_xor(m, 1));

    // Pass 2: sum of exp2(t - m)
    float s = 0.0f;
    #pragma unroll 8
    for (int j = lane; j < NPTS; j += LANES) {
        float4 t4 = tile[j];
        float dx = rp.x - t4.x, dy = rp.y - t4.y;
        float c = fmaf(dy, dy, dx * dx);
        float t = fmaf(nscale, c, t4.z);
        s += FAST_EXP2(t - m);
    }
    s += __shfl_xor(s, 8);
    s += __shfl_xor(s, 4);
    s += __shfl_xor(s, 2);
    s += __shfl_xor(s, 1);

    if (lane == 0) {
        const float LN2 = 0.69314718055994531f;
        float sm = -eps * LN2 * (m + FAST_LOG2(s));
        int idx = batch * NPTS + row;
        outPot[idx] = c_old * ownPrev[idx] + c_new * sm;
    }
}

__global__ void log_precompute(const float* __restrict__ a, const float* __restrict__ b,
                               float* __restrict__ loga, float* __restrict__ logb, int n)
{
    int i = blockIdx.x * blockDim.x + threadIdx.x;
    if (i < n) {
        loga[i] = logf(a[i]);
        logb[i] = logf(b[i]);
    }
}

__global__ __launch_bounds__(1024) void loss_reduce(
    const float* __restrict__ a, const float* __restrict__ bw,
    const float* __restrict__ f, const float* __restrict__ g,
    float* __restrict__ out)
{
    float acc = 0.0f;
    for (int i = threadIdx.x; i < NE; i += 1024)
        acc += a[i] * f[i] + bw[i] * g[i];
    // wave64 reduce
    acc += __shfl_xor(acc, 32);
    acc += __shfl_xor(acc, 16);
    acc += __shfl_xor(acc, 8);
    acc += __shfl_xor(acc, 4);
    acc += __shfl_xor(acc, 2);
    acc += __shfl_xor(acc, 1);
    __shared__ float wsum[16];
    int wid = threadIdx.x >> 6;
    if ((threadIdx.x & 63) == 0) wsum[wid] = acc;
    __syncthreads();
    if (threadIdx.x < 16) {
        float v = wsum[threadIdx.x];
        v += __shfl_xor(v, 8, 16);
        v += __shfl_xor(v, 4, 16);
        v += __shfl_xor(v, 2, 16);
        v += __shfl_xor(v, 1, 16);
        if (threadIdx.x == 0) out[0] = v * (1.0f / NB);
    }
}

extern "C" void kernel_launch(void* const* d_in, const int* in_sizes, int n_in,
                              void* d_out, int out_size, void* d_ws, size_t ws_size,
                              hipStream_t stream)
{
    const float* a = (const float*)d_in[0];
    const float* x = (const float*)d_in[1];
    const float* b = (const float*)d_in[2];
    const float* y = (const float*)d_in[3];
    float* out = (float*)d_out;

    float* ws = (float*)d_ws;
    float* loga = ws + 0 * NE;
    float* logb = ws + 1 * NE;
    float* fA   = ws + 2 * NE;
    float* gA   = ws + 3 * NE;
    float* fB   = ws + 4 * NE;
    float* gB   = ws + 5 * NE;

    // eps annealing schedule (double on host, as in reference)
    double eps_list[32];
    int ne = 0;
    const double eps_final = 0.05 * 0.05;   // blur^p
    double eps = 2.0 * 2.0;                  // diameter^p
    while (eps > eps_final) { eps_list[ne++] = eps; eps *= 0.64; }  // scaling^p
    eps_list[ne++] = eps_final;              // ne == 18

    (void)hipMemsetAsync(fA, 0, NE * sizeof(float), stream);
    (void)hipMemsetAsync(gA, 0, NE * sizeof(float), stream);
    log_precompute<<<(NE + 255) / 256, 256, 0, stream>>>(a, b, loga, logb, NE);

    const float* fp = fA; const float* gp = gA;
    float* fn = fB; float* gn = gB;

    auto phase = [&](double e, float c_old, float c_new) {
        sinkhorn_phase<<<1024, THREADS, 0, stream>>>(
            x, y, loga, logb, fp, gp, fn, gn,
            (float)e, (float)(1.0 / e), c_old, c_new);
    };
    auto swapbuf = [&]() {
        const float* tf = fp; const float* tg = gp;
        fp = fn; gp = gn;
        fn = (float*)tf; gn = (float*)tg;
    };

    // init at eps0 (h uses g=0 / f=0, no damping)
    phase(eps_list[0], 0.0f, 1.0f);
    swapbuf();
    // annealed damped iterations
    for (int k = 0; k < ne; k++) {
        phase(eps_list[k], 0.5f, 0.5f);
        swapbuf();
    }
    // final extrapolation at eps_final (no damping)
    phase(eps_list[ne - 1], 0.0f, 1.0f);
    // result potentials are in fn, gn

    loss_reduce<<<1, 1024, 0, stream>>>(a, b, fn, gn, out);
}

// Round 3
// 375.946 us; speedup vs baseline: 2.1824x; 2.1824x over previous
//
#include <hip/hip_runtime.h>
#include <cmath>

#define NB 8
#define NPTS 2048
#define NE (NB * NPTS)
#define THREADS 512
#define ROWS_PER_WAVE 8

#if defined(__has_builtin)
#if __has_builtin(__builtin_amdgcn_exp2f)
#define FAST_EXP2(x) __builtin_amdgcn_exp2f(x)
#else
#define FAST_EXP2(x) exp2f(x)
#endif
#if __has_builtin(__builtin_amdgcn_logf)
#define FAST_LOG2(x) __builtin_amdgcn_logf(x)
#else
#define FAST_LOG2(x) log2f(x)
#endif
#else
#define FAST_EXP2(x) exp2f(x)
#define FAST_LOG2(x) log2f(x)
#endif

// One Sinkhorn "phase": for every row i of each batch (both sides),
//   softmin_eps(C, h)_i = -eps * LSE_j( h_j - C_ij/eps ),
// out = c_old*prev + c_new*softmin.
//
// Cost expansion: C_ij/eps = (|x_i|^2 + |y_j|^2 - 2 x_i.y_j) / (2 eps).
// Column constant hc_j = (h_j - |y_j|^2/(2eps)) * log2e  (staged in LDS),
// row constant hr_i = -|x_i|^2/(2eps)*log2e (added after the LSE),
// leaving the inner loop t = fma(rx, y.x, fma(ry, y.y, hc)).
__global__ __launch_bounds__(THREADS, 2) void sinkhorn_phase(
    const float* __restrict__ x, const float* __restrict__ y,
    const float* __restrict__ loga, const float* __restrict__ logb,
    const float* __restrict__ f_prev, const float* __restrict__ g_prev,
    float* __restrict__ f_next, float* __restrict__ g_next,
    float eps, float inv_eps, float c_old, float c_new)
{
    __shared__ float4 tile[NPTS];  // {y.x, y.y, hc (log2 domain), pad}

    const int blk = blockIdx.x;
    const int side = blk >> 8;          // 256 blocks per side
    const int rblk = blk & 255;
    const int batch = rblk >> 5;        // 32 row-tiles (of 64 rows) per batch
    const int rowTile = rblk & 31;

    const float* rowPts; const float* colPts; const float* hlog;
    const float* hpot; const float* ownPrev; float* outPot;
    if (side == 0) { rowPts = x; colPts = y; hlog = logb; hpot = g_prev; ownPrev = f_prev; outPot = f_next; }
    else           { rowPts = y; colPts = x; hlog = loga; hpot = f_prev; ownPrev = g_prev; outPot = g_next; }

    const float LOG2E = 1.4426950408889634f;
    const float LN2 = 0.69314718055994531f;

    // Stage columns + log2-domain h-constant into LDS.
    const float2* cp2 = (const float2*)(colPts + (size_t)batch * NPTS * 2);
    const float* hl = hlog + (size_t)batch * NPTS;
    const float* pp = hpot + (size_t)batch * NPTS;
    for (int j = threadIdx.x; j < NPTS; j += THREADS) {
        float2 p = cp2[j];
        float hcv = (hl[j] + pp[j] * inv_eps
                     - 0.5f * inv_eps * fmaf(p.x, p.x, p.y * p.y)) * LOG2E;
        tile[j] = make_float4(p.x, p.y, hcv, 0.0f);
    }
    __syncthreads();

    const int lane = threadIdx.x & 63;
    const int wv = threadIdx.x >> 6;                 // 8 waves/block
    const int row0 = rowTile * 64 + wv * ROWS_PER_WAVE;
    const float2* rp2 = (const float2*)(rowPts + (size_t)batch * NPTS * 2) + row0;

    const float sc = inv_eps * LOG2E;
    float rx[ROWS_PER_WAVE], ry[ROWS_PER_WAVE], hr[ROWS_PER_WAVE];
    #pragma unroll
    for (int r = 0; r < ROWS_PER_WAVE; r++) {
        float2 p = rp2[r];
        rx[r] = p.x * sc;
        ry[r] = p.y * sc;
        hr[r] = -0.5f * sc * fmaf(p.x, p.x, p.y * p.y);
    }

    // Pass 1: row maxima (log2 domain), 64 distinct j per wave-iter.
    float m[ROWS_PER_WAVE];
    #pragma unroll
    for (int r = 0; r < ROWS_PER_WAVE; r++) m[r] = -3.4e38f;
    #pragma unroll 4
    for (int it = 0; it < NPTS / 64; it++) {
        float4 t4 = tile[(it << 6) + lane];
        #pragma unroll
        for (int r = 0; r < ROWS_PER_WAVE; r++) {
            float t = fmaf(rx[r], t4.x, fmaf(ry[r], t4.y, t4.z));
            m[r] = fmaxf(m[r], t);
        }
    }
    #pragma unroll
    for (int r = 0; r < ROWS_PER_WAVE; r++) {
        m[r] = fmaxf(m[r], __shfl_xor(m[r], 32));
        m[r] = fmaxf(m[r], __shfl_xor(m[r], 16));
        m[r] = fmaxf(m[r], __shfl_xor(m[r], 8));
        m[r] = fmaxf(m[r], __shfl_xor(m[r], 4));
        m[r] = fmaxf(m[r], __shfl_xor(m[r], 2));
        m[r] = fmaxf(m[r], __shfl_xor(m[r], 1));
    }

    // Pass 2: sum of exp2(t - m).
    float s[ROWS_PER_WAVE];
    #pragma unroll
    for (int r = 0; r < ROWS_PER_WAVE; r++) s[r] = 0.0f;
    #pragma unroll 4
    for (int it = 0; it < NPTS / 64; it++) {
        float4 t4 = tile[(it << 6) + lane];
        #pragma unroll
        for (int r = 0; r < ROWS_PER_WAVE; r++) {
            float t = fmaf(rx[r], t4.x, fmaf(ry[r], t4.y, t4.z));
            s[r] += FAST_EXP2(t - m[r]);
        }
    }
    #pragma unroll
    for (int r = 0; r < ROWS_PER_WAVE; r++) {
        s[r] += __shfl_xor(s[r], 32);
        s[r] += __shfl_xor(s[r], 16);
        s[r] += __shfl_xor(s[r], 8);
        s[r] += __shfl_xor(s[r], 4);
        s[r] += __shfl_xor(s[r], 2);
        s[r] += __shfl_xor(s[r], 1);
    }

    if (lane == 0) {
        const int idx0 = batch * NPTS + row0;
        #pragma unroll
        for (int r = 0; r < ROWS_PER_WAVE; r++) {
            float sm = -eps * LN2 * (hr[r] + m[r] + FAST_LOG2(s[r]));
            outPot[idx0 + r] = c_old * ownPrev[idx0 + r] + c_new * sm;
        }
    }
}

__global__ void log_precompute(const float* __restrict__ a, const float* __restrict__ b,
                               float* __restrict__ loga, float* __restrict__ logb, int n)
{
    int i = blockIdx.x * blockDim.x + threadIdx.x;
    if (i < n) {
        loga[i] = logf(a[i]);
        logb[i] = logf(b[i]);
    }
}

__global__ __launch_bounds__(1024) void loss_reduce(
    const float* __restrict__ a, const float* __restrict__ bw,
    const float* __restrict__ f, const float* __restrict__ g,
    float* __restrict__ out)
{
    float acc = 0.0f;
    for (int i = threadIdx.x; i < NE; i += 1024)
        acc += a[i] * f[i] + bw[i] * g[i];
    acc += __shfl_xor(acc, 32);
    acc += __shfl_xor(acc, 16);
    acc += __shfl_xor(acc, 8);
    acc += __shfl_xor(acc, 4);
    acc += __shfl_xor(acc, 2);
    acc += __shfl_xor(acc, 1);
    __shared__ float wsum[16];
    int wid = threadIdx.x >> 6;
    if ((threadIdx.x & 63) == 0) wsum[wid] = acc;
    __syncthreads();
    if (threadIdx.x < 16) {
        float v = wsum[threadIdx.x];
        v += __shfl_xor(v, 8, 16);
        v += __shfl_xor(v, 4, 16);
        v += __shfl_xor(v, 2, 16);
        v += __shfl_xor(v, 1, 16);
        if (threadIdx.x == 0) out[0] = v * (1.0f / NB);
    }
}

extern "C" void kernel_launch(void* const* d_in, const int* in_sizes, int n_in,
                              void* d_out, int out_size, void* d_ws, size_t ws_size,
                              hipStream_t stream)
{
    const float* a = (const float*)d_in[0];
    const float* x = (const float*)d_in[1];
    const float* b = (const float*)d_in[2];
    const float* y = (const float*)d_in[3];
    float* out = (float*)d_out;

    float* ws = (float*)d_ws;
    float* loga = ws + 0 * NE;
    float* logb = ws + 1 * NE;
    float* fA   = ws + 2 * NE;
    float* gA   = ws + 3 * NE;
    float* fB   = ws + 4 * NE;
    float* gB   = ws + 5 * NE;

    // eps annealing schedule (double on host, as in reference)
    double eps_list[32];
    int ne = 0;
    const double eps_final = 0.05 * 0.05;   // blur^p
    double eps = 2.0 * 2.0;                  // diameter^p
    while (eps > eps_final) { eps_list[ne++] = eps; eps *= 0.64; }  // scaling^p
    eps_list[ne++] = eps_final;              // ne == 18

    (void)hipMemsetAsync(fA, 0, NE * sizeof(float), stream);
    (void)hipMemsetAsync(gA, 0, NE * sizeof(float), stream);
    log_precompute<<<(NE + 255) / 256, 256, 0, stream>>>(a, b, loga, logb, NE);

    const float* fp = fA; const float* gp = gA;
    float* fn = fB; float* gn = gB;

    auto phase = [&](double e, float c_old, float c_new) {
        sinkhorn_phase<<<512, THREADS, 0, stream>>>(
            x, y, loga, logb, fp, gp, fn, gn,
            (float)e, (float)(1.0 / e), c_old, c_new);
    };
    auto swapbuf = [&]() {
        const float* tf = fp; const float* tg = gp;
        fp = fn; gp = gn;
        fn = (float*)tf; gn = (float*)tg;
    };

    // init at eps0 (h uses g=0 / f=0, no damping)
    phase(eps_list[0], 0.0f, 1.0f);
    swapbuf();
    // annealed damped iterations
    for (int k = 0; k < ne; k++) {
        phase(eps_list[k], 0.5f, 0.5f);
        swapbuf();
    }
    // final extrapolation at eps_final (no damping)
    phase(eps_list[ne - 1], 0.0f, 1.0f);
    // result potentials are in fn, gn

    loss_reduce<<<1, 1024, 0, stream>>>(a, b, fn, gn, out);
}